// Round 9
// baseline (234.554 us; speedup 1.0000x reference)
//
#include <hip/hip_runtime.h>
#include <hip/hip_bf16.h>

// ---------------------------------------------------------------------------
// CouchesintermediairesGNN — R16:
//  R15 post-mortem: nodeb pinned at 75.0-75.2us for 3 rounds; VGPR stayed 32
//  after the manual 4-edge body -> compiler SANK each LOADXD back into its
//  STEPQ (register minimization), so the ILP experiment never ran.
//  FIX (single variable): __builtin_amdgcn_sched_barrier(0) between the
//  4-gather load cluster and the 4-STEP compute cluster. Scheduler cannot
//  sink loads past it -> 4 gathers in flight/thread, one waitcnt.
//  Decisive: VGPR must rise to ~52-64. If dur drops -> chain-latency theory
//  confirmed. If dur unchanged with VGPR up -> nodeb is throughput-bound by
//  an occupancy/ILP-invariant resource; kernels at structural floor.
//  Kept: BATCH 4096, XCD sub-cursors, padded cursors, 40B-packed xa,
//  channel-QUAD walk, full-bucket 512-thr nodeb.
//  Pipeline: memset(gcursor) + k_scatter + k_nodeb (3 dispatches).
// ---------------------------------------------------------------------------

#define BATCH 4096
#define BPT   16      // edges per thread in scatter (BATCH/256)
#define BSH   7       // 128 nodes per bucket
#define CAP   4608    // LDS edge capacity per bucket (avg 4092, +8 sigma)
#define CAP8  640     // sub-region capacity (mean 512, +5.7 sigma)
#define GST   16      // cursor stride in ints (64B: one line per counter)

__device__ inline float blo(unsigned v) { return __uint_as_float(v << 16); }
__device__ inline float bhi(unsigned v) { return __uint_as_float(v & 0xFFFF0000u); }
__device__ inline unsigned f2bfu(float f) {
    __hip_bfloat16 h = __float2bfloat16(f);
    unsigned short us;
    __builtin_memcpy(&us, &h, 2);
    return (unsigned)us;
}

// exclusive block scan of data[0..n), 256 threads, n<=1024; returns total
__device__ int block_scan_excl(int* data, int n, int* scratch) {
    const int t = threadIdx.x;
    const int lane = t & 63, w = t >> 6;
    const int base = t * 4;
    int v0 = (base + 0 < n) ? data[base + 0] : 0;
    int v1 = (base + 1 < n) ? data[base + 1] : 0;
    int v2 = (base + 2 < n) ? data[base + 2] : 0;
    int v3 = (base + 3 < n) ? data[base + 3] : 0;
    int p1 = v0 + v1, p2 = p1 + v2, p3 = p2 + v3;
    int x = p3;
    #pragma unroll
    for (int o = 1; o < 64; o <<= 1) { int y = __shfl_up(x, o); if (lane >= o) x += y; }
    if (lane == 63) scratch[w] = x;
    __syncthreads();
    int wbase = 0;
    for (int i = 0; i < w; ++i) wbase += scratch[i];
    int tb = wbase + x - p3;
    if (base + 0 < n) data[base + 0] = tb;
    if (base + 1 < n) data[base + 1] = tb + v0;
    if (base + 2 < n) data[base + 2] = tb + p1;
    if (base + 3 < n) data[base + 3] = tb + p2;
    int tot = scratch[0] + scratch[1] + scratch[2] + scratch[3];
    __syncthreads();
    return tot;
}

// single-pass LDS-batched scatter into XCD-partitioned bucket sub-regions.
// block 0 additionally computes AB/flag; tail does the packed bf16 x-pack.
__launch_bounds__(256)
__global__ void k_scatter(const int* __restrict__ src, const int* __restrict__ dst,
                          const float* __restrict__ ea, int* __restrict__ gcursor,
                          int2* __restrict__ tmp,
                          const float* __restrict__ x, unsigned* __restrict__ xau,
                          const float* __restrict__ W1, const float* __restrict__ b1,
                          const float* __restrict__ W2, const float* __restrict__ b2,
                          float* __restrict__ AB, int* __restrict__ flag,
                          int E, int nb, int Npack, int EH, int EO) {
    __shared__ int2 pay2[BATCH];              // 32 KB (word, (bucket<<7)|nlow)
    __shared__ int  lcount[1024];             // counts -> exclusive offsets
    __shared__ int  lsave[1024];              // counts -> sub-region bases
    __shared__ int  scratch[4];
    const int t = threadIdx.x;
    const int xcd = blockIdx.x & 7;           // round-robin XCD heuristic

    if (blockIdx.x == 0) {                    // fused param precompute
        if (t == 64) {
            int ok = 1;
            for (int k = 0; k < EH; ++k) if (b1[k] != 0.0f) ok = 0;
            *flag = ok;
        }
        if (t < EO) {
            float A = 0.0f;
            for (int k = 0; k < EH; ++k)
                if (W1[k] > 0.0f) A = fmaf(W1[k], W2[k * EO + t], A);
            AB[t]      = A;
            AB[EO + t] = b2[t];
        }
    }

    for (int i = t; i < 1024; i += 256) lcount[i] = 0;
    __syncthreads();
    const int base = blockIdx.x * BATCH;
    int mys[BPT], myr[BPT], myw[BPT];
    #pragma unroll
    for (int k = 0; k < BPT; ++k) {
        int e = base + k * 256 + t;           // lane-strided: coalesced
        mys[k] = -1;
        if (e < E) {
            int s = src[e], d = dst[e];
            float dd = ea[e];
            int ib = (int)(dd * 10.0f);
            ib = ib < 0 ? 0 : (ib > 9 ? 9 : ib);
            int dq = (int)fmaf(dd, 2047.0f, 0.5f);
            dq = dq < 0 ? 0 : (dq > 2047 ? 2047 : dq);
            mys[k] = s;
            myr[k] = atomicAdd(&lcount[s >> BSH], 1);
            myw[k] = (d & 0x1FFFF) | (ib << 17) | (dq << 21);
        }
    }
    __syncthreads();
    for (int i = t; i < 1024; i += 256) lsave[i] = lcount[i];
    __syncthreads();
    int total = block_scan_excl(lcount, nb, scratch);   // lcount -> excl offsets
    for (int b = t; b < nb; b += 256) {
        int c = lsave[b];
        if (c > 0) lsave[b] = atomicAdd(&gcursor[(b * 8 + xcd) * GST], c);
    }
    __syncthreads();
    #pragma unroll
    for (int k = 0; k < BPT; ++k) {
        if (mys[k] >= 0) {
            int b = mys[k] >> BSH;
            int pos = lcount[b] + myr[k];
            pay2[pos] = make_int2(myw[k], (b << 7) | (mys[k] & 127));
        }
    }
    __syncthreads();
    // bucket-grouped burst writes into sub-region (b*8+xcd)*CAP8
    for (int j = t; j < total; j += 256) {
        int2 v = pay2[j];
        int bb = v.y >> 7;
        int pos = lsave[bb] + (j - lcount[bb]);
        if (pos < CAP8) tmp[(size_t)(bb * 8 + xcd) * CAP8 + pos] = v;
    }
    // fused packed bf16 x-pack (grid-stride); Npack==0 disables.
    // xau[n*10+p] = bf16 pair (ch 2p, 2p+1) of node n -> 40B rows, 4.0MB total
    const int stride = gridDim.x * 256;
    for (int i = blockIdx.x * 256 + t; i < Npack * 10; i += stride) {
        int n = i / 10, p = i - n * 10;
        float2 v = *(const float2*)(x + n * 40 + p * 2);
        xau[i] = f2bfu(v.x) | (f2bfu(v.y) << 16);
    }
}

// fused per-bucket bin + node update: one block per 128-node bucket, 512 thr
template <int USE_XA>
__launch_bounds__(512, 6)
__global__ void k_nodeb(const float* __restrict__ x,
                        const unsigned* __restrict__ xau,
                        const int* __restrict__ gcount,
                        const int2* __restrict__ tmp,
                        const float* __restrict__ a_p, const float* __restrict__ b_p,
                        const float* __restrict__ g1, const float* __restrict__ g2,
                        const float* __restrict__ bias,
                        const float* __restrict__ AB, const int* __restrict__ flag_p,
                        const float* __restrict__ W1, const float* __restrict__ b1,
                        const float* __restrict__ W2, const float* __restrict__ b2,
                        float* __restrict__ out, int N, int EH, int EO) {
    __shared__ int   buf[CAP];                  // 18 KB packed edges by node
    __shared__ int   hist[128];
    __shared__ int   rowstart[129];
    __shared__ int   lcur[128];
    __shared__ unsigned char perm[128];         // rows sorted by length desc
    __shared__ int   segm[8];                   // per-sub-region edge counts
    __shared__ int   cps[9];                    // cumulative pair prefix
    __shared__ __hip_bfloat16 s_x0[128 * 22];   // 5.5 KB
    __shared__ float s_sf[128 * 21];            // 10.5 KB
    __shared__ float s_g1[20 * 21], s_g2[20 * 21], s_b[20];

    const int t = threadIdx.x;
    const int b = blockIdx.x;
    const int node0 = b << BSH;

    if (t < 128) hist[t] = 0;
    // wave 0: segment counts + cumulative pair prefix (visible after barrier)
    if (t < 64) {
        int c = (t < 8) ? gcount[(b * 8 + t) * GST] : 0;
        c = c > CAP8 ? CAP8 : c;
        int pr = (c + 1) >> 1;
        int acc = pr;
        #pragma unroll
        for (int o = 1; o < 8; o <<= 1) { int y = __shfl_up(acc, o); if (t >= o) acc += y; }
        if (t < 8) { segm[t] = c; cps[t] = acc - pr; }
        if (t == 7) cps[8] = acc;
    }
    for (int i = t; i < 400; i += 512) {
        int r = i / 20, cc = i - r * 20;
        s_g1[r * 21 + cc] = g1[i];
        s_g2[r * 21 + cc] = g2[i];
    }
    if (t < 20) s_b[t] = bias[t];
    // stage x[:,0] rows for this bucket (bf16)
    if (USE_XA) {
        for (int i = t; i < 1280; i += 512) {            // uint pair loads
            int l = i / 10, p = i - l * 10;
            int n = node0 + l;
            unsigned v = (n < N) ? xau[n * 10 + p] : 0u;
            *(unsigned*)&s_x0[l * 22 + 2 * p] = v;
        }
    } else {
        for (int i = t; i < 2560; i += 512) {
            int l = i / 20, cc = i - l * 20;
            int n = node0 + l;
            s_x0[l * 22 + cc] = __float2bfloat16((n < N) ? x[n * 40 + cc] : 0.0f);
        }
    }
    __syncthreads();

    // vectorized staged read across 8 sub-regions via concatenated pair index
    const int TP = cps[8];                      // total int4 pairs, <= 2560
    int vw[10], vn[10];
    #pragma unroll
    for (int k = 0; k < 5; ++k) {
        int pidx = k * 512 + t;
        vn[k * 2 + 0] = -1;
        vn[k * 2 + 1] = -1;
        if (pidx < TP) {
            int r = 0;
            #pragma unroll
            for (int rr = 1; rr < 8; ++rr) if (pidx >= cps[rr]) r = rr;
            int lp = pidx - cps[r];
            int mr = segm[r];
            const int4* sp = (const int4*)(tmp + (size_t)(b * 8 + r) * CAP8);
            int4 wv = sp[lp];
            int e0 = lp << 1;
            vw[k * 2 + 0] = wv.x;
            vw[k * 2 + 1] = wv.z;
            { vn[k * 2 + 0] = wv.y & 127; atomicAdd(&hist[vn[k * 2 + 0]], 1); }
            if (e0 + 1 < mr) { vn[k * 2 + 1] = wv.w & 127; atomicAdd(&hist[vn[k * 2 + 1]], 1); }
        }
    }
    __syncthreads();
    // wave-0 exclusive scan of 128 counts (each lane owns 2)
    if (t < 64) {
        int a = hist[2 * t], bb = hist[2 * t + 1];
        int s = a + bb;
        int xsc = s;
        #pragma unroll
        for (int o = 1; o < 64; o <<= 1) { int y = __shfl_up(xsc, o); if (t >= o) xsc += y; }
        int excl = xsc - s;
        rowstart[2 * t]     = excl;
        rowstart[2 * t + 1] = excl + a;
        lcur[2 * t]         = excl;
        lcur[2 * t + 1]     = excl + a;
        if (t == 63) rowstart[128] = xsc;     // total staged
    }
    __syncthreads();
    // bin packed words into buf (grouped by node within bucket)
    #pragma unroll
    for (int k = 0; k < 10; ++k) {
        if (vn[k] >= 0) {
            int p = atomicAdd(&lcur[vn[k]], 1);
            if (p < CAP) buf[p] = vw[k];
        }
    }
    __syncthreads();

    // length-sort rows (descending) so each wave walks similar-length rows
    if (t < 128) hist[t] = 0;
    __syncthreads();
    if (t < 128) {
        int len = rowstart[t + 1] - rowstart[t];
        int bin = 127 - (len > 127 ? 127 : len);
        atomicAdd(&hist[bin], 1);
    }
    __syncthreads();
    if (t < 64) {
        int a = hist[2 * t], bb = hist[2 * t + 1];
        int s = a + bb;
        int xsc = s;
        #pragma unroll
        for (int o = 1; o < 64; o <<= 1) { int y = __shfl_up(xsc, o); if (t >= o) xsc += y; }
        int excl = xsc - s;
        hist[2 * t]     = excl;
        hist[2 * t + 1] = excl + a;
    }
    __syncthreads();
    if (t < 128) {
        int len = rowstart[t + 1] - rowstart[t];
        int bin = 127 - (len > 127 ? 127 : len);
        int pos = atomicAdd(&hist[bin], 1);
        perm[pos] = (unsigned char)t;
    }

    const float av = a_p[0], bv = b_p[0];
    const float am1 = 1.0f - av;
    const int fl = *flag_p;
    __syncthreads();

    // phase B: channel-QUAD row walk, 640 items = 128 rows x 5 quads.
    // 4-edge body; sched_barrier(0) pins the 4-gather cluster ABOVE compute.
    const uint2* xg = (const uint2*)xau;

#define LOADXD(w_, y0_, y1_, y2_, y3_)                                   \
    {                                                                    \
        if (USE_XA) {                                                    \
            uint2 v_ = xg[(unsigned)((w_) & 0x1FFFF) * 5u + (unsigned)q];\
            y0_ = blo(v_.x); y1_ = bhi(v_.x);                            \
            y2_ = blo(v_.y); y3_ = bhi(v_.y);                            \
        } else {                                                         \
            int n_ = (w_) & 0x1FFFF;                                     \
            y0_ = x[n_ * 40 + c0];     y1_ = x[n_ * 40 + c0 + 1];        \
            y2_ = x[n_ * 40 + c0 + 2]; y3_ = x[n_ * 40 + c0 + 3];        \
        }                                                                \
    }
#define STEPQ(w_, y0_, y1_, y2_, y3_)                                    \
    {                                                                    \
        int   ib_  = ((w_) >> 17) & 0xF;                                 \
        float dqf_ = (float)(((unsigned)(w_)) >> 21);                    \
        float r0_ = exp2f(bv * __log2f(fabsf(fmaf(-am1, y0_, pax0))));   \
        float r1_ = exp2f(bv * __log2f(fabsf(fmaf(-am1, y1_, pax1))));   \
        float r2_ = exp2f(bv * __log2f(fabsf(fmaf(-am1, y2_, pax2))));   \
        float r3_ = exp2f(bv * __log2f(fabsf(fmaf(-am1, y3_, pax3))));   \
        float e0_ = cl0 ? ((ib_ == c0)     ? 1.0f : 0.0f) : dqf_;        \
        float e1_ = cl1 ? ((ib_ == c0 + 1) ? 1.0f : 0.0f) : dqf_;        \
        float e2_ = cl2 ? ((ib_ == c0 + 2) ? 1.0f : 0.0f) : dqf_;        \
        float e3_ = cl3 ? ((ib_ == c0 + 3) ? 1.0f : 0.0f) : dqf_;        \
        sA0 += e0_; sB0 = fmaf(r0_, e0_, sB0); s20 += r0_;               \
        sA1 += e1_; sB1 = fmaf(r1_, e1_, sB1); s21 += r1_;               \
        sA2 += e2_; sB2 = fmaf(r2_, e2_, sB2); s22 += r2_;               \
        sA3 += e3_; sB3 = fmaf(r3_, e3_, sB3); s23 += r3_;               \
    }

    #pragma unroll
    for (int r = 0; r < 2; ++r) {
        int item = t + 512 * r;
        if (item >= 640) break;                // wave-uniform (128 = 2 waves)
        int li = perm[item / 5];
        int q  = item - (item / 5) * 5;
        int c0 = q * 4;                        // channels c0..c0+3
        const bool cl0 = (c0 + 0) < 10, cl1 = (c0 + 1) < 10;
        const bool cl2 = (c0 + 2) < 10, cl3 = (c0 + 3) < 10;
        unsigned xv0 = *(const unsigned*)&s_x0[li * 22 + c0];
        unsigned xv1 = *(const unsigned*)&s_x0[li * 22 + c0 + 2];
        const float pax0 = av * blo(xv0), pax1 = av * bhi(xv0);
        const float pax2 = av * blo(xv1), pax3 = av * bhi(xv1);
        int rs = rowstart[li];
        int re = rowstart[li + 1];
        float deg = (float)(re - rs);
        float sf0, sf1, sf2, sf3;
        if (fl || (c0 + 3) < 10) {
            float sA0 = 0.f, sB0 = 0.f, s20 = 0.f;
            float sA1 = 0.f, sB1 = 0.f, s21 = 0.f;
            float sA2 = 0.f, sB2 = 0.f, s22 = 0.f;
            float sA3 = 0.f, sB3 = 0.f, s23 = 0.f;
            int i = rs;
            for (; i + 4 <= re; i += 4) {
                int w0 = buf[i], w1 = buf[i + 1], w2 = buf[i + 2], w3 = buf[i + 3];
                float a0, a1, a2, a3, b0, b1, b2, b3;
                float c0x, c1x, c2x, c3x, d0, d1, d2, d3;
                LOADXD(w0, a0, a1, a2, a3);
                LOADXD(w1, b0, b1, b2, b3);
                LOADXD(w2, c0x, c1x, c2x, c3x);
                LOADXD(w3, d0, d1, d2, d3);
                __builtin_amdgcn_sched_barrier(0);   // loads stay ABOVE
                STEPQ(w0, a0, a1, a2, a3);
                STEPQ(w1, b0, b1, b2, b3);
                STEPQ(w2, c0x, c1x, c2x, c3x);
                STEPQ(w3, d0, d1, d2, d3);
            }
            for (; i < re; ++i) {
                int w0 = buf[i];
                float a0, a1, a2, a3;
                LOADXD(w0, a0, a1, a2, a3);
                STEPQ(w0, a0, a1, a2, a3);
            }
            #define FIN(K, sAk, sBk, s2k, sfk)                                     \
            {   int ck = c0 + K;                                                   \
                float sw, s1;                                                      \
                if (ck < 10) { sw = sAk; s1 = sBk; }                               \
                else { float Afq = AB[ck - 10] * (1.0f / 2047.0f);                 \
                       float Bf  = AB[ck];                                         \
                       sw = fmaf(Afq, sAk, Bf * deg);                              \
                       s1 = fmaf(Afq, sBk, Bf * s2k); }                            \
                sfk = (sw != 0.0f) ? (s1 / sw) : (0.01f * s2k);                    \
            }
            FIN(0, sA0, sB0, s20, sf0); FIN(1, sA1, sB1, s21, sf1);
            FIN(2, sA2, sB2, s22, sf2); FIN(3, sA3, sB3, s23, sf3);
            #undef FIN
        } else {
            // exact fallback (b1 != 0): full per-edge MLP, generic per channel
            float swk[4] = {0.f, 0.f, 0.f, 0.f};
            float s1k[4] = {0.f, 0.f, 0.f, 0.f};
            float s2k[4] = {0.f, 0.f, 0.f, 0.f};
            float paxs[4] = {pax0, pax1, pax2, pax3};
            for (int i = rs; i < re; ++i) {
                int w = buf[i];
                float xd[4];
                LOADXD(w, xd[0], xd[1], xd[2], xd[3]);
                int   ib  = (w >> 17) & 0xF;
                float dd_ = (float)(((unsigned)w) >> 21) * (1.0f / 2047.0f);
                float mlp[4];
                #pragma unroll
                for (int kk = 0; kk < 4; ++kk) {
                    int ck = c0 + kk;
                    mlp[kk] = b2[ck >= 10 ? ck - 10 : 0];
                }
                for (int k_ = 0; k_ < EH; ++k_) {
                    float h_ = fmaf(dd_, W1[k_], b1[k_]);
                    h_ = h_ > 0.0f ? h_ : 0.0f;
                    #pragma unroll
                    for (int kk = 0; kk < 4; ++kk) {
                        int ck = c0 + kk;
                        mlp[kk] = fmaf(h_, W2[k_ * EO + (ck >= 10 ? ck - 10 : 0)], mlp[kk]);
                    }
                }
                #pragma unroll
                for (int kk = 0; kk < 4; ++kk) {
                    int ck = c0 + kk;
                    float rho = exp2f(bv * __log2f(fabsf(fmaf(-am1, xd[kk], paxs[kk]))));
                    float sel = (ck < 10) ? ((ib == ck) ? 1.0f : 0.0f) : mlp[kk];
                    swk[kk] += sel;
                    s1k[kk] = fmaf(rho, sel, s1k[kk]);
                    s2k[kk] += rho;
                }
            }
            sf0 = (swk[0] != 0.0f) ? (s1k[0] / swk[0]) : (0.01f * s2k[0]);
            sf1 = (swk[1] != 0.0f) ? (s1k[1] / swk[1]) : (0.01f * s2k[1]);
            sf2 = (swk[2] != 0.0f) ? (s1k[2] / swk[2]) : (0.01f * s2k[2]);
            sf3 = (swk[3] != 0.0f) ? (s1k[3] / swk[3]) : (0.01f * s2k[3]);
        }
        s_sf[li * 21 + c0]     = sf0;
        s_sf[li * 21 + c0 + 1] = sf1;
        s_sf[li * 21 + c0 + 2] = sf2;
        s_sf[li * 21 + c0 + 3] = sf3;
    }
    #undef LOADXD
    #undef STEPQ
    __syncthreads();

    // epilogue: out0 = sigmoid(x0 @ g1^T + sf @ g2^T + bias); out1 = sf
    for (int i = t; i < 2560; i += 512) {
        int l = i / 20, cc = i - l * 20;
        int n = node0 + l;
        if (n < N) {
            float acc = s_b[cc];
            const __hip_bfloat16* xr = &s_x0[l * 22];
            const float* sr  = &s_sf[l * 21];
            const float* g1r = &s_g1[cc * 21];
            const float* g2r = &s_g2[cc * 21];
            #pragma unroll
            for (int k = 0; k < 20; ++k)
                acc = fmaf(__bfloat162float(xr[k]), g1r[k], fmaf(sr[k], g2r[k], acc));
            float o0 = 1.0f / (1.0f + __expf(-acc));
            out[n * 40 + cc]      = o0;
            out[n * 40 + 20 + cc] = sr[cc];
        }
    }
}

extern "C" void kernel_launch(void* const* d_in, const int* in_sizes, int n_in,
                              void* d_out, int out_size, void* d_ws, size_t ws_size,
                              hipStream_t stream) {
    const float* x    = (const float*)d_in[0];
    const int*   ei   = (const int*)  d_in[1];
    const float* ea   = (const float*)d_in[2];
    const float* a_p  = (const float*)d_in[3];
    const float* b_p  = (const float*)d_in[4];
    const float* g1   = (const float*)d_in[5];
    const float* g2   = (const float*)d_in[6];
    const float* bias = (const float*)d_in[7];
    const float* W1   = (const float*)d_in[8];
    const float* b1   = (const float*)d_in[9];
    const float* W2   = (const float*)d_in[10];
    const float* b2   = (const float*)d_in[11];
    float* out = (float*)d_out;

    const int E  = in_sizes[2];
    const int N  = in_sizes[0] / 40;   // x is [N,2,20]
    const int EH = in_sizes[8];        // 64
    const int EO = in_sizes[11];       // 10
    const int* src = ei;
    const int* dst = ei + E;

    const int nb     = (N + 127) >> BSH;          // 782
    const int nbatch = (E + BATCH - 1) / BATCH;   // 782

    // workspace layout (bytes)
    char* wsb = (char*)d_ws;
    size_t o = 0;
    int* gcursor = (int*)(wsb + o); o += (size_t)nb * 8 * GST * 4;  // sub-cursors
    float* AB    = (float*)(wsb + o); o += 2 * (size_t)EO * 4;
    int* flag    = (int*)(wsb + o);   o += 4;                   o = (o + 15) & ~(size_t)15;
    int2* tmp    = (int2*)(wsb + o);  o += (size_t)nb * 8 * CAP8 * 8;   // 16B-aligned
    unsigned* xau = (unsigned*)(wsb + o);          // packed bf16 pairs, 40B/node
    const size_t need_xa = o + (size_t)N * 10 * 4;
    const int use_xa = (ws_size >= need_xa) ? 1 : 0;

    hipMemsetAsync(gcursor, 0, (size_t)nb * 8 * GST * sizeof(int), stream);

    k_scatter<<<nbatch, 256, 0, stream>>>(src, dst, ea, gcursor, tmp,
                                          x, use_xa ? xau : (unsigned*)AB,
                                          W1, b1, W2, b2, AB, flag,
                                          E, nb, use_xa ? N : 0, EH, EO);
    if (use_xa) {
        k_nodeb<1><<<nb, 512, 0, stream>>>(x, xau, gcursor, tmp, a_p, b_p,
                                           g1, g2, bias, AB, flag,
                                           W1, b1, W2, b2, out, N, EH, EO);
    } else {
        k_nodeb<0><<<nb, 512, 0, stream>>>(x, xau, gcursor, tmp, a_p, b_p,
                                           g1, g2, bias, AB, flag,
                                           W1, b1, W2, b2, out, N, EH, EO);
    }
}

// Round 10
// 223.921 us; speedup vs baseline: 1.0475x; 1.0475x over previous
//
#include <hip/hip_runtime.h>
#include <hip/hip_bf16.h>

// ---------------------------------------------------------------------------
// CouchesintermediairesGNN — R17:
//  R16 post-mortem: sched_barrier pinned 16 live floats -> scratch spills
//  (WRITE +7.8MB, FETCH +21MB), 75->87us. REVERTED. Series evidence:
//  nodeb invariant to instr count (R10), occupancy (R14) -> latency-chain
//  bound: each lane serially walks ~32-45 edges, each gated by a dependent
//  ~250cy L2 gather, ~3 waves/SIMD.
//  FIX: HALF-ROW segments. items = 128 rows x 5 quads x 2 halves = 1280;
//  partner lanes (2k,2k+1) walk [rs,mid)/[mid,re), then combine the 12
//  partial accumulators via __shfl_xor(.,1) (no LDS, ~24 instr). Serial
//  chain per wave halves. Registers/thread unchanged -> no spills.
//  Kept: R15 everything else (BATCH 4096, XCD sub-cursors, padded cursors,
//  40B-packed xa, 4-edge unroll without sched_barrier).
//  Pipeline: memset(gcursor) + k_scatter + k_nodeb (3 dispatches).
// ---------------------------------------------------------------------------

#define BATCH 4096
#define BPT   16      // edges per thread in scatter (BATCH/256)
#define BSH   7       // 128 nodes per bucket
#define CAP   4608    // LDS edge capacity per bucket (avg 4092, +8 sigma)
#define CAP8  640     // sub-region capacity (mean 512, +5.7 sigma)
#define GST   16      // cursor stride in ints (64B: one line per counter)

__device__ inline float blo(unsigned v) { return __uint_as_float(v << 16); }
__device__ inline float bhi(unsigned v) { return __uint_as_float(v & 0xFFFF0000u); }
__device__ inline unsigned f2bfu(float f) {
    __hip_bfloat16 h = __float2bfloat16(f);
    unsigned short us;
    __builtin_memcpy(&us, &h, 2);
    return (unsigned)us;
}

// exclusive block scan of data[0..n), 256 threads, n<=1024; returns total
__device__ int block_scan_excl(int* data, int n, int* scratch) {
    const int t = threadIdx.x;
    const int lane = t & 63, w = t >> 6;
    const int base = t * 4;
    int v0 = (base + 0 < n) ? data[base + 0] : 0;
    int v1 = (base + 1 < n) ? data[base + 1] : 0;
    int v2 = (base + 2 < n) ? data[base + 2] : 0;
    int v3 = (base + 3 < n) ? data[base + 3] : 0;
    int p1 = v0 + v1, p2 = p1 + v2, p3 = p2 + v3;
    int x = p3;
    #pragma unroll
    for (int o = 1; o < 64; o <<= 1) { int y = __shfl_up(x, o); if (lane >= o) x += y; }
    if (lane == 63) scratch[w] = x;
    __syncthreads();
    int wbase = 0;
    for (int i = 0; i < w; ++i) wbase += scratch[i];
    int tb = wbase + x - p3;
    if (base + 0 < n) data[base + 0] = tb;
    if (base + 1 < n) data[base + 1] = tb + v0;
    if (base + 2 < n) data[base + 2] = tb + p1;
    if (base + 3 < n) data[base + 3] = tb + p2;
    int tot = scratch[0] + scratch[1] + scratch[2] + scratch[3];
    __syncthreads();
    return tot;
}

// single-pass LDS-batched scatter into XCD-partitioned bucket sub-regions.
// block 0 additionally computes AB/flag; tail does the packed bf16 x-pack.
__launch_bounds__(256)
__global__ void k_scatter(const int* __restrict__ src, const int* __restrict__ dst,
                          const float* __restrict__ ea, int* __restrict__ gcursor,
                          int2* __restrict__ tmp,
                          const float* __restrict__ x, unsigned* __restrict__ xau,
                          const float* __restrict__ W1, const float* __restrict__ b1,
                          const float* __restrict__ W2, const float* __restrict__ b2,
                          float* __restrict__ AB, int* __restrict__ flag,
                          int E, int nb, int Npack, int EH, int EO) {
    __shared__ int2 pay2[BATCH];              // 32 KB (word, (bucket<<7)|nlow)
    __shared__ int  lcount[1024];             // counts -> exclusive offsets
    __shared__ int  lsave[1024];              // counts -> sub-region bases
    __shared__ int  scratch[4];
    const int t = threadIdx.x;
    const int xcd = blockIdx.x & 7;           // round-robin XCD heuristic

    if (blockIdx.x == 0) {                    // fused param precompute
        if (t == 64) {
            int ok = 1;
            for (int k = 0; k < EH; ++k) if (b1[k] != 0.0f) ok = 0;
            *flag = ok;
        }
        if (t < EO) {
            float A = 0.0f;
            for (int k = 0; k < EH; ++k)
                if (W1[k] > 0.0f) A = fmaf(W1[k], W2[k * EO + t], A);
            AB[t]      = A;
            AB[EO + t] = b2[t];
        }
    }

    for (int i = t; i < 1024; i += 256) lcount[i] = 0;
    __syncthreads();
    const int base = blockIdx.x * BATCH;
    int mys[BPT], myr[BPT], myw[BPT];
    #pragma unroll
    for (int k = 0; k < BPT; ++k) {
        int e = base + k * 256 + t;           // lane-strided: coalesced
        mys[k] = -1;
        if (e < E) {
            int s = src[e], d = dst[e];
            float dd = ea[e];
            int ib = (int)(dd * 10.0f);
            ib = ib < 0 ? 0 : (ib > 9 ? 9 : ib);
            int dq = (int)fmaf(dd, 2047.0f, 0.5f);
            dq = dq < 0 ? 0 : (dq > 2047 ? 2047 : dq);
            mys[k] = s;
            myr[k] = atomicAdd(&lcount[s >> BSH], 1);
            myw[k] = (d & 0x1FFFF) | (ib << 17) | (dq << 21);
        }
    }
    __syncthreads();
    for (int i = t; i < 1024; i += 256) lsave[i] = lcount[i];
    __syncthreads();
    int total = block_scan_excl(lcount, nb, scratch);   // lcount -> excl offsets
    for (int b = t; b < nb; b += 256) {
        int c = lsave[b];
        if (c > 0) lsave[b] = atomicAdd(&gcursor[(b * 8 + xcd) * GST], c);
    }
    __syncthreads();
    #pragma unroll
    for (int k = 0; k < BPT; ++k) {
        if (mys[k] >= 0) {
            int b = mys[k] >> BSH;
            int pos = lcount[b] + myr[k];
            pay2[pos] = make_int2(myw[k], (b << 7) | (mys[k] & 127));
        }
    }
    __syncthreads();
    // bucket-grouped burst writes into sub-region (b*8+xcd)*CAP8
    for (int j = t; j < total; j += 256) {
        int2 v = pay2[j];
        int bb = v.y >> 7;
        int pos = lsave[bb] + (j - lcount[bb]);
        if (pos < CAP8) tmp[(size_t)(bb * 8 + xcd) * CAP8 + pos] = v;
    }
    // fused packed bf16 x-pack (grid-stride); Npack==0 disables.
    // xau[n*10+p] = bf16 pair (ch 2p, 2p+1) of node n -> 40B rows, 4.0MB total
    const int stride = gridDim.x * 256;
    for (int i = blockIdx.x * 256 + t; i < Npack * 10; i += stride) {
        int n = i / 10, p = i - n * 10;
        float2 v = *(const float2*)(x + n * 40 + p * 2);
        xau[i] = f2bfu(v.x) | (f2bfu(v.y) << 16);
    }
}

// fused per-bucket bin + node update: one block per 128-node bucket, 512 thr
template <int USE_XA>
__launch_bounds__(512, 6)
__global__ void k_nodeb(const float* __restrict__ x,
                        const unsigned* __restrict__ xau,
                        const int* __restrict__ gcount,
                        const int2* __restrict__ tmp,
                        const float* __restrict__ a_p, const float* __restrict__ b_p,
                        const float* __restrict__ g1, const float* __restrict__ g2,
                        const float* __restrict__ bias,
                        const float* __restrict__ AB, const int* __restrict__ flag_p,
                        const float* __restrict__ W1, const float* __restrict__ b1,
                        const float* __restrict__ W2, const float* __restrict__ b2,
                        float* __restrict__ out, int N, int EH, int EO) {
    __shared__ int   buf[CAP];                  // 18 KB packed edges by node
    __shared__ int   hist[128];
    __shared__ int   rowstart[129];
    __shared__ int   lcur[128];
    __shared__ unsigned char perm[128];         // rows sorted by length desc
    __shared__ int   segm[8];                   // per-sub-region edge counts
    __shared__ int   cps[9];                    // cumulative pair prefix
    __shared__ __hip_bfloat16 s_x0[128 * 22];   // 5.5 KB
    __shared__ float s_sf[128 * 21];            // 10.5 KB
    __shared__ float s_g1[20 * 21], s_g2[20 * 21], s_b[20];

    const int t = threadIdx.x;
    const int b = blockIdx.x;
    const int node0 = b << BSH;

    if (t < 128) hist[t] = 0;
    // wave 0: segment counts + cumulative pair prefix (visible after barrier)
    if (t < 64) {
        int c = (t < 8) ? gcount[(b * 8 + t) * GST] : 0;
        c = c > CAP8 ? CAP8 : c;
        int pr = (c + 1) >> 1;
        int acc = pr;
        #pragma unroll
        for (int o = 1; o < 8; o <<= 1) { int y = __shfl_up(acc, o); if (t >= o) acc += y; }
        if (t < 8) { segm[t] = c; cps[t] = acc - pr; }
        if (t == 7) cps[8] = acc;
    }
    for (int i = t; i < 400; i += 512) {
        int r = i / 20, cc = i - r * 20;
        s_g1[r * 21 + cc] = g1[i];
        s_g2[r * 21 + cc] = g2[i];
    }
    if (t < 20) s_b[t] = bias[t];
    // stage x[:,0] rows for this bucket (bf16)
    if (USE_XA) {
        for (int i = t; i < 1280; i += 512) {            // uint pair loads
            int l = i / 10, p = i - l * 10;
            int n = node0 + l;
            unsigned v = (n < N) ? xau[n * 10 + p] : 0u;
            *(unsigned*)&s_x0[l * 22 + 2 * p] = v;
        }
    } else {
        for (int i = t; i < 2560; i += 512) {
            int l = i / 20, cc = i - l * 20;
            int n = node0 + l;
            s_x0[l * 22 + cc] = __float2bfloat16((n < N) ? x[n * 40 + cc] : 0.0f);
        }
    }
    __syncthreads();

    // vectorized staged read across 8 sub-regions via concatenated pair index
    const int TP = cps[8];                      // total int4 pairs, <= 2560
    int vw[10], vn[10];
    #pragma unroll
    for (int k = 0; k < 5; ++k) {
        int pidx = k * 512 + t;
        vn[k * 2 + 0] = -1;
        vn[k * 2 + 1] = -1;
        if (pidx < TP) {
            int r = 0;
            #pragma unroll
            for (int rr = 1; rr < 8; ++rr) if (pidx >= cps[rr]) r = rr;
            int lp = pidx - cps[r];
            int mr = segm[r];
            const int4* sp = (const int4*)(tmp + (size_t)(b * 8 + r) * CAP8);
            int4 wv = sp[lp];
            int e0 = lp << 1;
            vw[k * 2 + 0] = wv.x;
            vw[k * 2 + 1] = wv.z;
            { vn[k * 2 + 0] = wv.y & 127; atomicAdd(&hist[vn[k * 2 + 0]], 1); }
            if (e0 + 1 < mr) { vn[k * 2 + 1] = wv.w & 127; atomicAdd(&hist[vn[k * 2 + 1]], 1); }
        }
    }
    __syncthreads();
    // wave-0 exclusive scan of 128 counts (each lane owns 2)
    if (t < 64) {
        int a = hist[2 * t], bb = hist[2 * t + 1];
        int s = a + bb;
        int xsc = s;
        #pragma unroll
        for (int o = 1; o < 64; o <<= 1) { int y = __shfl_up(xsc, o); if (t >= o) xsc += y; }
        int excl = xsc - s;
        rowstart[2 * t]     = excl;
        rowstart[2 * t + 1] = excl + a;
        lcur[2 * t]         = excl;
        lcur[2 * t + 1]     = excl + a;
        if (t == 63) rowstart[128] = xsc;     // total staged
    }
    __syncthreads();
    // bin packed words into buf (grouped by node within bucket)
    #pragma unroll
    for (int k = 0; k < 10; ++k) {
        if (vn[k] >= 0) {
            int p = atomicAdd(&lcur[vn[k]], 1);
            if (p < CAP) buf[p] = vw[k];
        }
    }
    __syncthreads();

    // length-sort rows (descending) so each wave walks similar-length rows
    if (t < 128) hist[t] = 0;
    __syncthreads();
    if (t < 128) {
        int len = rowstart[t + 1] - rowstart[t];
        int bin = 127 - (len > 127 ? 127 : len);
        atomicAdd(&hist[bin], 1);
    }
    __syncthreads();
    if (t < 64) {
        int a = hist[2 * t], bb = hist[2 * t + 1];
        int s = a + bb;
        int xsc = s;
        #pragma unroll
        for (int o = 1; o < 64; o <<= 1) { int y = __shfl_up(xsc, o); if (t >= o) xsc += y; }
        int excl = xsc - s;
        hist[2 * t]     = excl;
        hist[2 * t + 1] = excl + a;
    }
    __syncthreads();
    if (t < 128) {
        int len = rowstart[t + 1] - rowstart[t];
        int bin = 127 - (len > 127 ? 127 : len);
        int pos = atomicAdd(&hist[bin], 1);
        perm[pos] = (unsigned char)t;
    }

    const float av = a_p[0], bv = b_p[0];
    const float am1 = 1.0f - av;
    const int fl = *flag_p;
    __syncthreads();

    // phase B: HALF-ROW channel-QUAD walk, 1280 items = 128 rows x 5 quads
    // x 2 halves. Partner lanes (2k,2k+1) walk [rs,mid)/[mid,re), combine
    // the 12 partial sums via shfl_xor(.,1). Serial gather chain halves.
    const uint2* xg = (const uint2*)xau;

#define LOADXD(w_, y0_, y1_, y2_, y3_)                                   \
    {                                                                    \
        if (USE_XA) {                                                    \
            uint2 v_ = xg[(unsigned)((w_) & 0x1FFFF) * 5u + (unsigned)q];\
            y0_ = blo(v_.x); y1_ = bhi(v_.x);                            \
            y2_ = blo(v_.y); y3_ = bhi(v_.y);                            \
        } else {                                                         \
            int n_ = (w_) & 0x1FFFF;                                     \
            y0_ = x[n_ * 40 + c0];     y1_ = x[n_ * 40 + c0 + 1];        \
            y2_ = x[n_ * 40 + c0 + 2]; y3_ = x[n_ * 40 + c0 + 3];        \
        }                                                                \
    }
#define STEPQ(w_, y0_, y1_, y2_, y3_)                                    \
    {                                                                    \
        int   ib_  = ((w_) >> 17) & 0xF;                                 \
        float dqf_ = (float)(((unsigned)(w_)) >> 21);                    \
        float r0_ = exp2f(bv * __log2f(fabsf(fmaf(-am1, y0_, pax0))));   \
        float r1_ = exp2f(bv * __log2f(fabsf(fmaf(-am1, y1_, pax1))));   \
        float r2_ = exp2f(bv * __log2f(fabsf(fmaf(-am1, y2_, pax2))));   \
        float r3_ = exp2f(bv * __log2f(fabsf(fmaf(-am1, y3_, pax3))));   \
        float e0_ = cl0 ? ((ib_ == c0)     ? 1.0f : 0.0f) : dqf_;        \
        float e1_ = cl1 ? ((ib_ == c0 + 1) ? 1.0f : 0.0f) : dqf_;        \
        float e2_ = cl2 ? ((ib_ == c0 + 2) ? 1.0f : 0.0f) : dqf_;        \
        float e3_ = cl3 ? ((ib_ == c0 + 3) ? 1.0f : 0.0f) : dqf_;        \
        sA0 += e0_; sB0 = fmaf(r0_, e0_, sB0); s20 += r0_;               \
        sA1 += e1_; sB1 = fmaf(r1_, e1_, sB1); s21 += r1_;               \
        sA2 += e2_; sB2 = fmaf(r2_, e2_, sB2); s22 += r2_;               \
        sA3 += e3_; sB3 = fmaf(r3_, e3_, sB3); s23 += r3_;               \
    }

    #pragma unroll
    for (int r = 0; r < 3; ++r) {
        int item = t + 512 * r;
        if (item >= 1280) break;               // wave-uniform (256 = 4 waves)
        int li = perm[item / 10];
        int rem = item - (item / 10) * 10;
        int q  = rem >> 1;                     // quad 0..4
        int sh = rem & 1;                      // half index
        int c0 = q * 4;                        // channels c0..c0+3
        const bool cl0 = (c0 + 0) < 10, cl1 = (c0 + 1) < 10;
        const bool cl2 = (c0 + 2) < 10, cl3 = (c0 + 3) < 10;
        unsigned xv0 = *(const unsigned*)&s_x0[li * 22 + c0];
        unsigned xv1 = *(const unsigned*)&s_x0[li * 22 + c0 + 2];
        const float pax0 = av * blo(xv0), pax1 = av * bhi(xv0);
        const float pax2 = av * blo(xv1), pax3 = av * bhi(xv1);
        int rs0 = rowstart[li];
        int re0 = rowstart[li + 1];
        int mid = (rs0 + re0) >> 1;
        int rs = sh ? mid : rs0;
        int re = sh ? re0 : mid;
        float deg = (float)(re0 - rs0);
        float sf0, sf1, sf2, sf3;
        if (fl || (c0 + 3) < 10) {
            float sA0 = 0.f, sB0 = 0.f, s20 = 0.f;
            float sA1 = 0.f, sB1 = 0.f, s21 = 0.f;
            float sA2 = 0.f, sB2 = 0.f, s22 = 0.f;
            float sA3 = 0.f, sB3 = 0.f, s23 = 0.f;
            int i = rs;
            for (; i + 4 <= re; i += 4) {
                int w0 = buf[i], w1 = buf[i + 1], w2 = buf[i + 2], w3 = buf[i + 3];
                float a0, a1, a2, a3, b0, b1, b2, b3;
                float c0x, c1x, c2x, c3x, d0, d1, d2, d3;
                LOADXD(w0, a0, a1, a2, a3);
                LOADXD(w1, b0, b1, b2, b3);
                LOADXD(w2, c0x, c1x, c2x, c3x);
                LOADXD(w3, d0, d1, d2, d3);
                STEPQ(w0, a0, a1, a2, a3);
                STEPQ(w1, b0, b1, b2, b3);
                STEPQ(w2, c0x, c1x, c2x, c3x);
                STEPQ(w3, d0, d1, d2, d3);
            }
            for (; i < re; ++i) {
                int w0 = buf[i];
                float a0, a1, a2, a3;
                LOADXD(w0, a0, a1, a2, a3);
                STEPQ(w0, a0, a1, a2, a3);
            }
            // pair combine: partner lane walked the other half of the row
            sA0 += __shfl_xor(sA0, 1); sB0 += __shfl_xor(sB0, 1); s20 += __shfl_xor(s20, 1);
            sA1 += __shfl_xor(sA1, 1); sB1 += __shfl_xor(sB1, 1); s21 += __shfl_xor(s21, 1);
            sA2 += __shfl_xor(sA2, 1); sB2 += __shfl_xor(sB2, 1); s22 += __shfl_xor(s22, 1);
            sA3 += __shfl_xor(sA3, 1); sB3 += __shfl_xor(sB3, 1); s23 += __shfl_xor(s23, 1);
            #define FIN(K, sAk, sBk, s2k, sfk)                                     \
            {   int ck = c0 + K;                                                   \
                float sw, s1;                                                      \
                if (ck < 10) { sw = sAk; s1 = sBk; }                               \
                else { float Afq = AB[ck - 10] * (1.0f / 2047.0f);                 \
                       float Bf  = AB[ck];                                         \
                       sw = fmaf(Afq, sAk, Bf * deg);                              \
                       s1 = fmaf(Afq, sBk, Bf * s2k); }                            \
                sfk = (sw != 0.0f) ? (s1 / sw) : (0.01f * s2k);                    \
            }
            FIN(0, sA0, sB0, s20, sf0); FIN(1, sA1, sB1, s21, sf1);
            FIN(2, sA2, sB2, s22, sf2); FIN(3, sA3, sB3, s23, sf3);
            #undef FIN
        } else {
            // exact fallback (b1 != 0): full per-edge MLP, generic per channel
            float swk[4] = {0.f, 0.f, 0.f, 0.f};
            float s1k[4] = {0.f, 0.f, 0.f, 0.f};
            float s2k[4] = {0.f, 0.f, 0.f, 0.f};
            float paxs[4] = {pax0, pax1, pax2, pax3};
            for (int i = rs; i < re; ++i) {
                int w = buf[i];
                float xd[4];
                LOADXD(w, xd[0], xd[1], xd[2], xd[3]);
                int   ib  = (w >> 17) & 0xF;
                float dd_ = (float)(((unsigned)w) >> 21) * (1.0f / 2047.0f);
                float mlp[4];
                #pragma unroll
                for (int kk = 0; kk < 4; ++kk) {
                    int ck = c0 + kk;
                    mlp[kk] = b2[ck >= 10 ? ck - 10 : 0];
                }
                for (int k_ = 0; k_ < EH; ++k_) {
                    float h_ = fmaf(dd_, W1[k_], b1[k_]);
                    h_ = h_ > 0.0f ? h_ : 0.0f;
                    #pragma unroll
                    for (int kk = 0; kk < 4; ++kk) {
                        int ck = c0 + kk;
                        mlp[kk] = fmaf(h_, W2[k_ * EO + (ck >= 10 ? ck - 10 : 0)], mlp[kk]);
                    }
                }
                #pragma unroll
                for (int kk = 0; kk < 4; ++kk) {
                    int ck = c0 + kk;
                    float rho = exp2f(bv * __log2f(fabsf(fmaf(-am1, xd[kk], paxs[kk]))));
                    float sel = (ck < 10) ? ((ib == ck) ? 1.0f : 0.0f) : mlp[kk];
                    swk[kk] += sel;
                    s1k[kk] = fmaf(rho, sel, s1k[kk]);
                    s2k[kk] += rho;
                }
            }
            #pragma unroll
            for (int kk = 0; kk < 4; ++kk) {
                swk[kk] += __shfl_xor(swk[kk], 1);
                s1k[kk] += __shfl_xor(s1k[kk], 1);
                s2k[kk] += __shfl_xor(s2k[kk], 1);
            }
            sf0 = (swk[0] != 0.0f) ? (s1k[0] / swk[0]) : (0.01f * s2k[0]);
            sf1 = (swk[1] != 0.0f) ? (s1k[1] / swk[1]) : (0.01f * s2k[1]);
            sf2 = (swk[2] != 0.0f) ? (s1k[2] / swk[2]) : (0.01f * s2k[2]);
            sf3 = (swk[3] != 0.0f) ? (s1k[3] / swk[3]) : (0.01f * s2k[3]);
        }
        if (sh == 0) {
            s_sf[li * 21 + c0]     = sf0;
            s_sf[li * 21 + c0 + 1] = sf1;
            s_sf[li * 21 + c0 + 2] = sf2;
            s_sf[li * 21 + c0 + 3] = sf3;
        }
    }
    #undef LOADXD
    #undef STEPQ
    __syncthreads();

    // epilogue: out0 = sigmoid(x0 @ g1^T + sf @ g2^T + bias); out1 = sf
    for (int i = t; i < 2560; i += 512) {
        int l = i / 20, cc = i - l * 20;
        int n = node0 + l;
        if (n < N) {
            float acc = s_b[cc];
            const __hip_bfloat16* xr = &s_x0[l * 22];
            const float* sr  = &s_sf[l * 21];
            const float* g1r = &s_g1[cc * 21];
            const float* g2r = &s_g2[cc * 21];
            #pragma unroll
            for (int k = 0; k < 20; ++k)
                acc = fmaf(__bfloat162float(xr[k]), g1r[k], fmaf(sr[k], g2r[k], acc));
            float o0 = 1.0f / (1.0f + __expf(-acc));
            out[n * 40 + cc]      = o0;
            out[n * 40 + 20 + cc] = sr[cc];
        }
    }
}

extern "C" void kernel_launch(void* const* d_in, const int* in_sizes, int n_in,
                              void* d_out, int out_size, void* d_ws, size_t ws_size,
                              hipStream_t stream) {
    const float* x    = (const float*)d_in[0];
    const int*   ei   = (const int*)  d_in[1];
    const float* ea   = (const float*)d_in[2];
    const float* a_p  = (const float*)d_in[3];
    const float* b_p  = (const float*)d_in[4];
    const float* g1   = (const float*)d_in[5];
    const float* g2   = (const float*)d_in[6];
    const float* bias = (const float*)d_in[7];
    const float* W1   = (const float*)d_in[8];
    const float* b1   = (const float*)d_in[9];
    const float* W2   = (const float*)d_in[10];
    const float* b2   = (const float*)d_in[11];
    float* out = (float*)d_out;

    const int E  = in_sizes[2];
    const int N  = in_sizes[0] / 40;   // x is [N,2,20]
    const int EH = in_sizes[8];        // 64
    const int EO = in_sizes[11];       // 10
    const int* src = ei;
    const int* dst = ei + E;

    const int nb     = (N + 127) >> BSH;          // 782
    const int nbatch = (E + BATCH - 1) / BATCH;   // 782

    // workspace layout (bytes)
    char* wsb = (char*)d_ws;
    size_t o = 0;
    int* gcursor = (int*)(wsb + o); o += (size_t)nb * 8 * GST * 4;  // sub-cursors
    float* AB    = (float*)(wsb + o); o += 2 * (size_t)EO * 4;
    int* flag    = (int*)(wsb + o);   o += 4;                   o = (o + 15) & ~(size_t)15;
    int2* tmp    = (int2*)(wsb + o);  o += (size_t)nb * 8 * CAP8 * 8;   // 16B-aligned
    unsigned* xau = (unsigned*)(wsb + o);          // packed bf16 pairs, 40B/node
    const size_t need_xa = o + (size_t)N * 10 * 4;
    const int use_xa = (ws_size >= need_xa) ? 1 : 0;

    hipMemsetAsync(gcursor, 0, (size_t)nb * 8 * GST * sizeof(int), stream);

    k_scatter<<<nbatch, 256, 0, stream>>>(src, dst, ea, gcursor, tmp,
                                          x, use_xa ? xau : (unsigned*)AB,
                                          W1, b1, W2, b2, AB, flag,
                                          E, nb, use_xa ? N : 0, EH, EO);
    if (use_xa) {
        k_nodeb<1><<<nb, 512, 0, stream>>>(x, xau, gcursor, tmp, a_p, b_p,
                                           g1, g2, bias, AB, flag,
                                           W1, b1, W2, b2, out, N, EH, EO);
    } else {
        k_nodeb<0><<<nb, 512, 0, stream>>>(x, xau, gcursor, tmp, a_p, b_p,
                                           g1, g2, bias, AB, flag,
                                           W1, b1, W2, b2, out, N, EH, EO);
    }
}

// Round 11
// 219.244 us; speedup vs baseline: 1.0698x; 1.0213x over previous
//
#include <hip/hip_runtime.h>
#include <hip/hip_bf16.h>

// ---------------------------------------------------------------------------
// CouchesintermediairesGNN — R18 (= R15 restored, best measured: 220.46us):
//  R17 post-mortem: half-row split regressed nodeb 75->78.5 (2x distinct
//  lines per wave-gather). Invariance table for nodeb now complete:
//  instr count x0.5 (R10): ~0 | occupancy x2 (R14): 0 | forced ILP (R16):
//  spills -12us | chain x0.5 (R17): -3us. -> bound by divergent-gather
//  lane throughput (~16M scattered 8B reqs ~ 26us/CU floor) x thin-spread
//  VALU/trans mix; scatter pinned by sector-granular scattered writes +
//  atomics (occupancy-invariant, R14). Locking in the measured optimum.
//  Config: BATCH 4096 scatter w/ XCD sub-cursors (write-amp ~1x), padded
//  cursors, 40B-packed L2-resident xa, nodeb 512-thr full-bucket quad walk
//  with 4-edge unroll (compiler-scheduled).
//  Pipeline: memset(gcursor) + k_scatter + k_nodeb (3 dispatches).
// ---------------------------------------------------------------------------

#define BATCH 4096
#define BPT   16      // edges per thread in scatter (BATCH/256)
#define BSH   7       // 128 nodes per bucket
#define CAP   4608    // LDS edge capacity per bucket (avg 4092, +8 sigma)
#define CAP8  640     // sub-region capacity (mean 512, +5.7 sigma)
#define GST   16      // cursor stride in ints (64B: one line per counter)

__device__ inline float blo(unsigned v) { return __uint_as_float(v << 16); }
__device__ inline float bhi(unsigned v) { return __uint_as_float(v & 0xFFFF0000u); }
__device__ inline unsigned f2bfu(float f) {
    __hip_bfloat16 h = __float2bfloat16(f);
    unsigned short us;
    __builtin_memcpy(&us, &h, 2);
    return (unsigned)us;
}

// exclusive block scan of data[0..n), 256 threads, n<=1024; returns total
__device__ int block_scan_excl(int* data, int n, int* scratch) {
    const int t = threadIdx.x;
    const int lane = t & 63, w = t >> 6;
    const int base = t * 4;
    int v0 = (base + 0 < n) ? data[base + 0] : 0;
    int v1 = (base + 1 < n) ? data[base + 1] : 0;
    int v2 = (base + 2 < n) ? data[base + 2] : 0;
    int v3 = (base + 3 < n) ? data[base + 3] : 0;
    int p1 = v0 + v1, p2 = p1 + v2, p3 = p2 + v3;
    int x = p3;
    #pragma unroll
    for (int o = 1; o < 64; o <<= 1) { int y = __shfl_up(x, o); if (lane >= o) x += y; }
    if (lane == 63) scratch[w] = x;
    __syncthreads();
    int wbase = 0;
    for (int i = 0; i < w; ++i) wbase += scratch[i];
    int tb = wbase + x - p3;
    if (base + 0 < n) data[base + 0] = tb;
    if (base + 1 < n) data[base + 1] = tb + v0;
    if (base + 2 < n) data[base + 2] = tb + p1;
    if (base + 3 < n) data[base + 3] = tb + p2;
    int tot = scratch[0] + scratch[1] + scratch[2] + scratch[3];
    __syncthreads();
    return tot;
}

// single-pass LDS-batched scatter into XCD-partitioned bucket sub-regions.
// block 0 additionally computes AB/flag; tail does the packed bf16 x-pack.
__launch_bounds__(256)
__global__ void k_scatter(const int* __restrict__ src, const int* __restrict__ dst,
                          const float* __restrict__ ea, int* __restrict__ gcursor,
                          int2* __restrict__ tmp,
                          const float* __restrict__ x, unsigned* __restrict__ xau,
                          const float* __restrict__ W1, const float* __restrict__ b1,
                          const float* __restrict__ W2, const float* __restrict__ b2,
                          float* __restrict__ AB, int* __restrict__ flag,
                          int E, int nb, int Npack, int EH, int EO) {
    __shared__ int2 pay2[BATCH];              // 32 KB (word, (bucket<<7)|nlow)
    __shared__ int  lcount[1024];             // counts -> exclusive offsets
    __shared__ int  lsave[1024];              // counts -> sub-region bases
    __shared__ int  scratch[4];
    const int t = threadIdx.x;
    const int xcd = blockIdx.x & 7;           // round-robin XCD heuristic

    if (blockIdx.x == 0) {                    // fused param precompute
        if (t == 64) {
            int ok = 1;
            for (int k = 0; k < EH; ++k) if (b1[k] != 0.0f) ok = 0;
            *flag = ok;
        }
        if (t < EO) {
            float A = 0.0f;
            for (int k = 0; k < EH; ++k)
                if (W1[k] > 0.0f) A = fmaf(W1[k], W2[k * EO + t], A);
            AB[t]      = A;
            AB[EO + t] = b2[t];
        }
    }

    for (int i = t; i < 1024; i += 256) lcount[i] = 0;
    __syncthreads();
    const int base = blockIdx.x * BATCH;
    int mys[BPT], myr[BPT], myw[BPT];
    #pragma unroll
    for (int k = 0; k < BPT; ++k) {
        int e = base + k * 256 + t;           // lane-strided: coalesced
        mys[k] = -1;
        if (e < E) {
            int s = src[e], d = dst[e];
            float dd = ea[e];
            int ib = (int)(dd * 10.0f);
            ib = ib < 0 ? 0 : (ib > 9 ? 9 : ib);
            int dq = (int)fmaf(dd, 2047.0f, 0.5f);
            dq = dq < 0 ? 0 : (dq > 2047 ? 2047 : dq);
            mys[k] = s;
            myr[k] = atomicAdd(&lcount[s >> BSH], 1);
            myw[k] = (d & 0x1FFFF) | (ib << 17) | (dq << 21);
        }
    }
    __syncthreads();
    for (int i = t; i < 1024; i += 256) lsave[i] = lcount[i];
    __syncthreads();
    int total = block_scan_excl(lcount, nb, scratch);   // lcount -> excl offsets
    for (int b = t; b < nb; b += 256) {
        int c = lsave[b];
        if (c > 0) lsave[b] = atomicAdd(&gcursor[(b * 8 + xcd) * GST], c);
    }
    __syncthreads();
    #pragma unroll
    for (int k = 0; k < BPT; ++k) {
        if (mys[k] >= 0) {
            int b = mys[k] >> BSH;
            int pos = lcount[b] + myr[k];
            pay2[pos] = make_int2(myw[k], (b << 7) | (mys[k] & 127));
        }
    }
    __syncthreads();
    // bucket-grouped burst writes into sub-region (b*8+xcd)*CAP8
    for (int j = t; j < total; j += 256) {
        int2 v = pay2[j];
        int bb = v.y >> 7;
        int pos = lsave[bb] + (j - lcount[bb]);
        if (pos < CAP8) tmp[(size_t)(bb * 8 + xcd) * CAP8 + pos] = v;
    }
    // fused packed bf16 x-pack (grid-stride); Npack==0 disables.
    // xau[n*10+p] = bf16 pair (ch 2p, 2p+1) of node n -> 40B rows, 4.0MB total
    const int stride = gridDim.x * 256;
    for (int i = blockIdx.x * 256 + t; i < Npack * 10; i += stride) {
        int n = i / 10, p = i - n * 10;
        float2 v = *(const float2*)(x + n * 40 + p * 2);
        xau[i] = f2bfu(v.x) | (f2bfu(v.y) << 16);
    }
}

// fused per-bucket bin + node update: one block per 128-node bucket, 512 thr
template <int USE_XA>
__launch_bounds__(512, 6)
__global__ void k_nodeb(const float* __restrict__ x,
                        const unsigned* __restrict__ xau,
                        const int* __restrict__ gcount,
                        const int2* __restrict__ tmp,
                        const float* __restrict__ a_p, const float* __restrict__ b_p,
                        const float* __restrict__ g1, const float* __restrict__ g2,
                        const float* __restrict__ bias,
                        const float* __restrict__ AB, const int* __restrict__ flag_p,
                        const float* __restrict__ W1, const float* __restrict__ b1,
                        const float* __restrict__ W2, const float* __restrict__ b2,
                        float* __restrict__ out, int N, int EH, int EO) {
    __shared__ int   buf[CAP];                  // 18 KB packed edges by node
    __shared__ int   hist[128];
    __shared__ int   rowstart[129];
    __shared__ int   lcur[128];
    __shared__ unsigned char perm[128];         // rows sorted by length desc
    __shared__ int   segm[8];                   // per-sub-region edge counts
    __shared__ int   cps[9];                    // cumulative pair prefix
    __shared__ __hip_bfloat16 s_x0[128 * 22];   // 5.5 KB
    __shared__ float s_sf[128 * 21];            // 10.5 KB
    __shared__ float s_g1[20 * 21], s_g2[20 * 21], s_b[20];

    const int t = threadIdx.x;
    const int b = blockIdx.x;
    const int node0 = b << BSH;

    if (t < 128) hist[t] = 0;
    // wave 0: segment counts + cumulative pair prefix (visible after barrier)
    if (t < 64) {
        int c = (t < 8) ? gcount[(b * 8 + t) * GST] : 0;
        c = c > CAP8 ? CAP8 : c;
        int pr = (c + 1) >> 1;
        int acc = pr;
        #pragma unroll
        for (int o = 1; o < 8; o <<= 1) { int y = __shfl_up(acc, o); if (t >= o) acc += y; }
        if (t < 8) { segm[t] = c; cps[t] = acc - pr; }
        if (t == 7) cps[8] = acc;
    }
    for (int i = t; i < 400; i += 512) {
        int r = i / 20, cc = i - r * 20;
        s_g1[r * 21 + cc] = g1[i];
        s_g2[r * 21 + cc] = g2[i];
    }
    if (t < 20) s_b[t] = bias[t];
    // stage x[:,0] rows for this bucket (bf16)
    if (USE_XA) {
        for (int i = t; i < 1280; i += 512) {            // uint pair loads
            int l = i / 10, p = i - l * 10;
            int n = node0 + l;
            unsigned v = (n < N) ? xau[n * 10 + p] : 0u;
            *(unsigned*)&s_x0[l * 22 + 2 * p] = v;
        }
    } else {
        for (int i = t; i < 2560; i += 512) {
            int l = i / 20, cc = i - l * 20;
            int n = node0 + l;
            s_x0[l * 22 + cc] = __float2bfloat16((n < N) ? x[n * 40 + cc] : 0.0f);
        }
    }
    __syncthreads();

    // vectorized staged read across 8 sub-regions via concatenated pair index
    const int TP = cps[8];                      // total int4 pairs, <= 2560
    int vw[10], vn[10];
    #pragma unroll
    for (int k = 0; k < 5; ++k) {
        int pidx = k * 512 + t;
        vn[k * 2 + 0] = -1;
        vn[k * 2 + 1] = -1;
        if (pidx < TP) {
            int r = 0;
            #pragma unroll
            for (int rr = 1; rr < 8; ++rr) if (pidx >= cps[rr]) r = rr;
            int lp = pidx - cps[r];
            int mr = segm[r];
            const int4* sp = (const int4*)(tmp + (size_t)(b * 8 + r) * CAP8);
            int4 wv = sp[lp];
            int e0 = lp << 1;
            vw[k * 2 + 0] = wv.x;
            vw[k * 2 + 1] = wv.z;
            { vn[k * 2 + 0] = wv.y & 127; atomicAdd(&hist[vn[k * 2 + 0]], 1); }
            if (e0 + 1 < mr) { vn[k * 2 + 1] = wv.w & 127; atomicAdd(&hist[vn[k * 2 + 1]], 1); }
        }
    }
    __syncthreads();
    // wave-0 exclusive scan of 128 counts (each lane owns 2)
    if (t < 64) {
        int a = hist[2 * t], bb = hist[2 * t + 1];
        int s = a + bb;
        int xsc = s;
        #pragma unroll
        for (int o = 1; o < 64; o <<= 1) { int y = __shfl_up(xsc, o); if (t >= o) xsc += y; }
        int excl = xsc - s;
        rowstart[2 * t]     = excl;
        rowstart[2 * t + 1] = excl + a;
        lcur[2 * t]         = excl;
        lcur[2 * t + 1]     = excl + a;
        if (t == 63) rowstart[128] = xsc;     // total staged
    }
    __syncthreads();
    // bin packed words into buf (grouped by node within bucket)
    #pragma unroll
    for (int k = 0; k < 10; ++k) {
        if (vn[k] >= 0) {
            int p = atomicAdd(&lcur[vn[k]], 1);
            if (p < CAP) buf[p] = vw[k];
        }
    }
    __syncthreads();

    // length-sort rows (descending) so each wave walks similar-length rows
    if (t < 128) hist[t] = 0;
    __syncthreads();
    if (t < 128) {
        int len = rowstart[t + 1] - rowstart[t];
        int bin = 127 - (len > 127 ? 127 : len);
        atomicAdd(&hist[bin], 1);
    }
    __syncthreads();
    if (t < 64) {
        int a = hist[2 * t], bb = hist[2 * t + 1];
        int s = a + bb;
        int xsc = s;
        #pragma unroll
        for (int o = 1; o < 64; o <<= 1) { int y = __shfl_up(xsc, o); if (t >= o) xsc += y; }
        int excl = xsc - s;
        hist[2 * t]     = excl;
        hist[2 * t + 1] = excl + a;
    }
    __syncthreads();
    if (t < 128) {
        int len = rowstart[t + 1] - rowstart[t];
        int bin = 127 - (len > 127 ? 127 : len);
        int pos = atomicAdd(&hist[bin], 1);
        perm[pos] = (unsigned char)t;
    }

    const float av = a_p[0], bv = b_p[0];
    const float am1 = 1.0f - av;
    const int fl = *flag_p;
    __syncthreads();

    // phase B: channel-QUAD row walk, 640 items = 128 rows x 5 quads.
    // 4-edge body, compiler-scheduled (R15 best-measured form).
    const uint2* xg = (const uint2*)xau;

#define LOADXD(w_, y0_, y1_, y2_, y3_)                                   \
    {                                                                    \
        if (USE_XA) {                                                    \
            uint2 v_ = xg[(unsigned)((w_) & 0x1FFFF) * 5u + (unsigned)q];\
            y0_ = blo(v_.x); y1_ = bhi(v_.x);                            \
            y2_ = blo(v_.y); y3_ = bhi(v_.y);                            \
        } else {                                                         \
            int n_ = (w_) & 0x1FFFF;                                     \
            y0_ = x[n_ * 40 + c0];     y1_ = x[n_ * 40 + c0 + 1];        \
            y2_ = x[n_ * 40 + c0 + 2]; y3_ = x[n_ * 40 + c0 + 3];        \
        }                                                                \
    }
#define STEPQ(w_, y0_, y1_, y2_, y3_)                                    \
    {                                                                    \
        int   ib_  = ((w_) >> 17) & 0xF;                                 \
        float dqf_ = (float)(((unsigned)(w_)) >> 21);                    \
        float r0_ = exp2f(bv * __log2f(fabsf(fmaf(-am1, y0_, pax0))));   \
        float r1_ = exp2f(bv * __log2f(fabsf(fmaf(-am1, y1_, pax1))));   \
        float r2_ = exp2f(bv * __log2f(fabsf(fmaf(-am1, y2_, pax2))));   \
        float r3_ = exp2f(bv * __log2f(fabsf(fmaf(-am1, y3_, pax3))));   \
        float e0_ = cl0 ? ((ib_ == c0)     ? 1.0f : 0.0f) : dqf_;        \
        float e1_ = cl1 ? ((ib_ == c0 + 1) ? 1.0f : 0.0f) : dqf_;        \
        float e2_ = cl2 ? ((ib_ == c0 + 2) ? 1.0f : 0.0f) : dqf_;        \
        float e3_ = cl3 ? ((ib_ == c0 + 3) ? 1.0f : 0.0f) : dqf_;        \
        sA0 += e0_; sB0 = fmaf(r0_, e0_, sB0); s20 += r0_;               \
        sA1 += e1_; sB1 = fmaf(r1_, e1_, sB1); s21 += r1_;               \
        sA2 += e2_; sB2 = fmaf(r2_, e2_, sB2); s22 += r2_;               \
        sA3 += e3_; sB3 = fmaf(r3_, e3_, sB3); s23 += r3_;               \
    }

    #pragma unroll
    for (int r = 0; r < 2; ++r) {
        int item = t + 512 * r;
        if (item >= 640) break;                // wave-uniform (128 = 2 waves)
        int li = perm[item / 5];
        int q  = item - (item / 5) * 5;
        int c0 = q * 4;                        // channels c0..c0+3
        const bool cl0 = (c0 + 0) < 10, cl1 = (c0 + 1) < 10;
        const bool cl2 = (c0 + 2) < 10, cl3 = (c0 + 3) < 10;
        unsigned xv0 = *(const unsigned*)&s_x0[li * 22 + c0];
        unsigned xv1 = *(const unsigned*)&s_x0[li * 22 + c0 + 2];
        const float pax0 = av * blo(xv0), pax1 = av * bhi(xv0);
        const float pax2 = av * blo(xv1), pax3 = av * bhi(xv1);
        int rs = rowstart[li];
        int re = rowstart[li + 1];
        float deg = (float)(re - rs);
        float sf0, sf1, sf2, sf3;
        if (fl || (c0 + 3) < 10) {
            float sA0 = 0.f, sB0 = 0.f, s20 = 0.f;
            float sA1 = 0.f, sB1 = 0.f, s21 = 0.f;
            float sA2 = 0.f, sB2 = 0.f, s22 = 0.f;
            float sA3 = 0.f, sB3 = 0.f, s23 = 0.f;
            int i = rs;
            for (; i + 4 <= re; i += 4) {
                int w0 = buf[i], w1 = buf[i + 1], w2 = buf[i + 2], w3 = buf[i + 3];
                float a0, a1, a2, a3, b0, b1, b2, b3;
                float c0x, c1x, c2x, c3x, d0, d1, d2, d3;
                LOADXD(w0, a0, a1, a2, a3);
                LOADXD(w1, b0, b1, b2, b3);
                LOADXD(w2, c0x, c1x, c2x, c3x);
                LOADXD(w3, d0, d1, d2, d3);
                STEPQ(w0, a0, a1, a2, a3);
                STEPQ(w1, b0, b1, b2, b3);
                STEPQ(w2, c0x, c1x, c2x, c3x);
                STEPQ(w3, d0, d1, d2, d3);
            }
            for (; i < re; ++i) {
                int w0 = buf[i];
                float a0, a1, a2, a3;
                LOADXD(w0, a0, a1, a2, a3);
                STEPQ(w0, a0, a1, a2, a3);
            }
            #define FIN(K, sAk, sBk, s2k, sfk)                                     \
            {   int ck = c0 + K;                                                   \
                float sw, s1;                                                      \
                if (ck < 10) { sw = sAk; s1 = sBk; }                               \
                else { float Afq = AB[ck - 10] * (1.0f / 2047.0f);                 \
                       float Bf  = AB[ck];                                         \
                       sw = fmaf(Afq, sAk, Bf * deg);                              \
                       s1 = fmaf(Afq, sBk, Bf * s2k); }                            \
                sfk = (sw != 0.0f) ? (s1 / sw) : (0.01f * s2k);                    \
            }
            FIN(0, sA0, sB0, s20, sf0); FIN(1, sA1, sB1, s21, sf1);
            FIN(2, sA2, sB2, s22, sf2); FIN(3, sA3, sB3, s23, sf3);
            #undef FIN
        } else {
            // exact fallback (b1 != 0): full per-edge MLP, generic per channel
            float swk[4] = {0.f, 0.f, 0.f, 0.f};
            float s1k[4] = {0.f, 0.f, 0.f, 0.f};
            float s2k[4] = {0.f, 0.f, 0.f, 0.f};
            float paxs[4] = {pax0, pax1, pax2, pax3};
            for (int i = rs; i < re; ++i) {
                int w = buf[i];
                float xd[4];
                LOADXD(w, xd[0], xd[1], xd[2], xd[3]);
                int   ib  = (w >> 17) & 0xF;
                float dd_ = (float)(((unsigned)w) >> 21) * (1.0f / 2047.0f);
                float mlp[4];
                #pragma unroll
                for (int kk = 0; kk < 4; ++kk) {
                    int ck = c0 + kk;
                    mlp[kk] = b2[ck >= 10 ? ck - 10 : 0];
                }
                for (int k_ = 0; k_ < EH; ++k_) {
                    float h_ = fmaf(dd_, W1[k_], b1[k_]);
                    h_ = h_ > 0.0f ? h_ : 0.0f;
                    #pragma unroll
                    for (int kk = 0; kk < 4; ++kk) {
                        int ck = c0 + kk;
                        mlp[kk] = fmaf(h_, W2[k_ * EO + (ck >= 10 ? ck - 10 : 0)], mlp[kk]);
                    }
                }
                #pragma unroll
                for (int kk = 0; kk < 4; ++kk) {
                    int ck = c0 + kk;
                    float rho = exp2f(bv * __log2f(fabsf(fmaf(-am1, xd[kk], paxs[kk]))));
                    float sel = (ck < 10) ? ((ib == ck) ? 1.0f : 0.0f) : mlp[kk];
                    swk[kk] += sel;
                    s1k[kk] = fmaf(rho, sel, s1k[kk]);
                    s2k[kk] += rho;
                }
            }
            sf0 = (swk[0] != 0.0f) ? (s1k[0] / swk[0]) : (0.01f * s2k[0]);
            sf1 = (swk[1] != 0.0f) ? (s1k[1] / swk[1]) : (0.01f * s2k[1]);
            sf2 = (swk[2] != 0.0f) ? (s1k[2] / swk[2]) : (0.01f * s2k[2]);
            sf3 = (swk[3] != 0.0f) ? (s1k[3] / swk[3]) : (0.01f * s2k[3]);
        }
        s_sf[li * 21 + c0]     = sf0;
        s_sf[li * 21 + c0 + 1] = sf1;
        s_sf[li * 21 + c0 + 2] = sf2;
        s_sf[li * 21 + c0 + 3] = sf3;
    }
    #undef LOADXD
    #undef STEPQ
    __syncthreads();

    // epilogue: out0 = sigmoid(x0 @ g1^T + sf @ g2^T + bias); out1 = sf
    for (int i = t; i < 2560; i += 512) {
        int l = i / 20, cc = i - l * 20;
        int n = node0 + l;
        if (n < N) {
            float acc = s_b[cc];
            const __hip_bfloat16* xr = &s_x0[l * 22];
            const float* sr  = &s_sf[l * 21];
            const float* g1r = &s_g1[cc * 21];
            const float* g2r = &s_g2[cc * 21];
            #pragma unroll
            for (int k = 0; k < 20; ++k)
                acc = fmaf(__bfloat162float(xr[k]), g1r[k], fmaf(sr[k], g2r[k], acc));
            float o0 = 1.0f / (1.0f + __expf(-acc));
            out[n * 40 + cc]      = o0;
            out[n * 40 + 20 + cc] = sr[cc];
        }
    }
}

extern "C" void kernel_launch(void* const* d_in, const int* in_sizes, int n_in,
                              void* d_out, int out_size, void* d_ws, size_t ws_size,
                              hipStream_t stream) {
    const float* x    = (const float*)d_in[0];
    const int*   ei   = (const int*)  d_in[1];
    const float* ea   = (const float*)d_in[2];
    const float* a_p  = (const float*)d_in[3];
    const float* b_p  = (const float*)d_in[4];
    const float* g1   = (const float*)d_in[5];
    const float* g2   = (const float*)d_in[6];
    const float* bias = (const float*)d_in[7];
    const float* W1   = (const float*)d_in[8];
    const float* b1   = (const float*)d_in[9];
    const float* W2   = (const float*)d_in[10];
    const float* b2   = (const float*)d_in[11];
    float* out = (float*)d_out;

    const int E  = in_sizes[2];
    const int N  = in_sizes[0] / 40;   // x is [N,2,20]
    const int EH = in_sizes[8];        // 64
    const int EO = in_sizes[11];       // 10
    const int* src = ei;
    const int* dst = ei + E;

    const int nb     = (N + 127) >> BSH;          // 782
    const int nbatch = (E + BATCH - 1) / BATCH;   // 782

    // workspace layout (bytes)
    char* wsb = (char*)d_ws;
    size_t o = 0;
    int* gcursor = (int*)(wsb + o); o += (size_t)nb * 8 * GST * 4;  // sub-cursors
    float* AB    = (float*)(wsb + o); o += 2 * (size_t)EO * 4;
    int* flag    = (int*)(wsb + o);   o += 4;                   o = (o + 15) & ~(size_t)15;
    int2* tmp    = (int2*)(wsb + o);  o += (size_t)nb * 8 * CAP8 * 8;   // 16B-aligned
    unsigned* xau = (unsigned*)(wsb + o);          // packed bf16 pairs, 40B/node
    const size_t need_xa = o + (size_t)N * 10 * 4;
    const int use_xa = (ws_size >= need_xa) ? 1 : 0;

    hipMemsetAsync(gcursor, 0, (size_t)nb * 8 * GST * sizeof(int), stream);

    k_scatter<<<nbatch, 256, 0, stream>>>(src, dst, ea, gcursor, tmp,
                                          x, use_xa ? xau : (unsigned*)AB,
                                          W1, b1, W2, b2, AB, flag,
                                          E, nb, use_xa ? N : 0, EH, EO);
    if (use_xa) {
        k_nodeb<1><<<nb, 512, 0, stream>>>(x, xau, gcursor, tmp, a_p, b_p,
                                           g1, g2, bias, AB, flag,
                                           W1, b1, W2, b2, out, N, EH, EO);
    } else {
        k_nodeb<0><<<nb, 512, 0, stream>>>(x, xau, gcursor, tmp, a_p, b_p,
                                           g1, g2, bias, AB, flag,
                                           W1, b1, W2, b2, out, N, EH, EO);
    }
}